// Round 1
// baseline (43.416 us; speedup 1.0000x reference)
//
#include <hip/hip_runtime.h>
#include <hip/hip_bf16.h>

// Problem constants (from reference): B=16, S=512, H=768.
#define BB 16
#define SS 512
#define HH 768
#define H4 (HH / 4)   // 192 float4 per row

// Kernel 1: mask_len[b] = sum over masks[b, :]
__global__ __launch_bounds__(256) void masklen_kernel(const int* __restrict__ masks,
                                                      int* __restrict__ mlen) {
    const int b = blockIdx.x;
    int sum = 0;
    for (int i = threadIdx.x; i < SS; i += blockDim.x)
        sum += masks[b * SS + i];
    // wave reduce (wave = 64)
    for (int off = 32; off > 0; off >>= 1)
        sum += __shfl_down(sum, off, 64);
    __shared__ int wsum[4];
    const int wid = threadIdx.x >> 6;
    const int lane = threadIdx.x & 63;
    if (lane == 0) wsum[wid] = sum;
    __syncthreads();
    if (threadIdx.x == 0) {
        int tot = 0;
        for (int w = 0; w < (int)(blockDim.x >> 6); ++w) tot += wsum[w];
        mlen[b] = tot;
    }
}

// Kernel 2: one block per (b, t); 192 threads each own one float4 column of H.
// out[b,t,:] = valid ? 0.25 * sum_{l<4} sum_{j=t+1}^{end-1} hidden[l,b,j,:] : 0
__global__ __launch_bounds__(192) void span_pool_kernel(const float* __restrict__ hidden,
                                                        const int* __restrict__ spans,
                                                        const int* __restrict__ mlen,
                                                        float* __restrict__ out) {
    const int t = blockIdx.x;
    const int b = blockIdx.y;
    const int h4 = threadIdx.x;  // 0..191

    float4 acc = make_float4(0.f, 0.f, 0.f, 0.f);

    const int ml = mlen[b];
    const bool valid = (t >= 1) && (t < ml - 1);
    if (valid) {
        const int span = spans[b * SS + t];
        const int start = t + 1;
        const int end = min(start + span, SS);
        #pragma unroll
        for (int l = 0; l < 4; ++l) {
            const float4* base =
                (const float4*)(hidden) + ((size_t)(l * BB + b) * SS) * H4;
            for (int j = start; j < end; ++j) {
                float4 v = base[(size_t)j * H4 + h4];
                acc.x += v.x; acc.y += v.y; acc.z += v.z; acc.w += v.w;
            }
        }
        acc.x *= 0.25f; acc.y *= 0.25f; acc.z *= 0.25f; acc.w *= 0.25f;
    }

    float4* o = (float4*)(out) + ((size_t)(b * SS + t)) * H4;
    o[h4] = acc;
}

extern "C" void kernel_launch(void* const* d_in, const int* in_sizes, int n_in,
                              void* d_out, int out_size, void* d_ws, size_t ws_size,
                              hipStream_t stream) {
    const float* hidden = (const float*)d_in[0];  // [4,B,S,H] f32
    const int* spans    = (const int*)d_in[1];    // [B,S] i32
    const int* masks    = (const int*)d_in[2];    // [B,S] i32
    float* out          = (float*)d_out;          // [B,S,H] f32
    int* mlen           = (int*)d_ws;             // [B] i32 scratch

    masklen_kernel<<<dim3(BB), dim3(256), 0, stream>>>(masks, mlen);

    dim3 grid(SS, BB);
    span_pool_kernel<<<grid, dim3(192), 0, stream>>>(hidden, spans, mlen, out);
}